// Round 3
// baseline (551.180 us; speedup 1.0000x reference)
//
#include <hip/hip_runtime.h>
#include <hip/hip_bf16.h>
#include <math.h>

// B=8 NC=64 N=128 DN=64 HS=HM=256 HMOD=64 MOD_IN=133 MOD_OUT=16512

typedef __bf16 bf16_t;
typedef __attribute__((ext_vector_type(8))) __bf16 bf16x8;
typedef __attribute__((ext_vector_type(4))) float f32x4;

__device__ __forceinline__ float fast_tanh(float x) {
  float e = __expf(2.0f * x);
  return 1.0f - 2.0f / (e + 1.0f);
}

__device__ __forceinline__ f32x4 mfma16(bf16x8 a, bf16x8 b, f32x4 c) {
  return __builtin_amdgcn_mfma_f32_16x16x32_bf16(a, b, c, 0, 0, 0);
}

// ---- K0: convert the 4 shared MLP weight matrices to bf16 ----
// layout in wbf: [0,49152) state_w1[256][192], [49152,65536) state_w2[64][256],
//                [65536,98304) msg_w1[256][128], [98304,114688) msg_w2[64][256]
__global__ __launch_bounds__(256) void k_convert(
    const float* __restrict__ sw1, const float* __restrict__ sw2,
    const float* __restrict__ mw1, const float* __restrict__ mw2,
    bf16_t* __restrict__ out) {
  int i = blockIdx.x * 256 + threadIdx.x;
  float v;
  if (i < 49152) v = sw1[i];
  else if (i < 65536) v = sw2[i - 49152];
  else if (i < 98304) v = mw1[i - 65536];
  else v = mw2[i - 98304];
  out[i] = (bf16_t)v;
}

// ---- K1: received = W @ msg (+inject on first 2 rows), plus sum|W| ----
__global__ __launch_bounds__(256) void k_received(
    const float* __restrict__ W, const float* __restrict__ msg,
    const float* __restrict__ Haug, const float* __restrict__ injw,
    const float* __restrict__ injb, float* __restrict__ rec,
    float* __restrict__ wstats) {
  int bc = blockIdx.x, c = bc & 63, b = bc >> 6;
  __shared__ bf16_t Wt[128][136];  // [i][j], padded stride for bank spread
  __shared__ bf16_t Mt[64][136];   // msg transposed: [d][j]
  __shared__ float inj[128];
  __shared__ float red[256];
  int t = threadIdx.x;
  const float* Wp = W + (size_t)bc * 16384;
  float asum = 0.f;
  for (int s = 0; s < 16; ++s) {
    int e = (s * 256 + t) * 4;
    f32x4 v = *(const f32x4*)(Wp + e);
    int i = e >> 7, j = e & 127;
#pragma unroll
    for (int u = 0; u < 4; ++u) { Wt[i][j + u] = (bf16_t)v[u]; asum += fabsf(v[u]); }
  }
  const float* Mp = msg + (size_t)bc * 8192;
  for (int s = 0; s < 8; ++s) {
    int e = (s * 256 + t) * 4;
    f32x4 v = *(const f32x4*)(Mp + e);
    int j = e >> 6, d = e & 63;
#pragma unroll
    for (int u = 0; u < 4; ++u) Mt[d + u][j] = (bf16_t)v[u];
  }
  if (t < 128) {  // inject[o] = sum_k cell[k]*inject_w[c][o][k] + inject_b[c][o]
    const float* cell = Haug + (size_t)b * 4096 + c * 64;
    const float* iw = injw + (size_t)c * 8192 + t * 64;
    float a = injb[c * 128 + t];
    for (int k = 0; k < 64; ++k) a += cell[k] * iw[k];
    inj[t] = a;
  }
  red[t] = asum;
  __syncthreads();
  for (int s = 128; s > 0; s >>= 1) {
    if (t < s) red[t] += red[t + s];
    __syncthreads();
  }
  if (t == 0) wstats[bc] = red[0];

  int wave = t >> 6, l = t & 63, lr = l & 15, kg = l >> 4;
  f32x4 acc[2][4] = {};
#pragma unroll
  for (int ks = 0; ks < 4; ++ks) {
    int kof = ks * 32 + kg * 8;
    bf16x8 a0 = *(const bf16x8*)&Wt[wave * 32 + lr][kof];
    bf16x8 a1 = *(const bf16x8*)&Wt[wave * 32 + 16 + lr][kof];
#pragma unroll
    for (int ni = 0; ni < 4; ++ni) {
      bf16x8 bfr = *(const bf16x8*)&Mt[ni * 16 + lr][kof];
      acc[0][ni] = mfma16(a0, bfr, acc[0][ni]);
      acc[1][ni] = mfma16(a1, bfr, acc[1][ni]);
    }
  }
  float* rp = rec + (size_t)bc * 8192;
#pragma unroll
  for (int mi = 0; mi < 2; ++mi)
#pragma unroll
    for (int ni = 0; ni < 4; ++ni)
#pragma unroll
      for (int r = 0; r < 4; ++r) {
        int row = wave * 32 + mi * 16 + kg * 4 + r, col = ni * 16 + lr;
        float v = acc[mi][ni][r];
        if (row < 2) v += inj[row * 64 + col];
        rp[row * 64 + col] = v;
      }
}

// ---- K2: fused state MLP + msg MLP, 64 rows per block, bf16 MFMA ----
__global__ __launch_bounds__(256) void k_mlp(
    const float* __restrict__ h, const float* __restrict__ rec,
    const float* __restrict__ nid, const bf16_t* __restrict__ wbf,
    const float* __restrict__ sb1, const float* __restrict__ sb2,
    const float* __restrict__ msb1, const float* __restrict__ msb2,
    float* __restrict__ out_h, float* __restrict__ out_m) {
  int blk = blockIdx.x;
  int bc = blk >> 1, c = bc & 63, half = blk & 1;
  __shared__ bf16_t xs[64][200];  // cols: 0-63 h, 64-127 received, 128-191 nid / hid2
  __shared__ bf16_t wc[64][200];  // weight chunk [h][k]
  __shared__ bf16_t hs[64][72];   // hid1 chunk, later h_new bf16 (wave-private rows)
  int t = threadIdx.x;
  size_t rowbase = (size_t)bc * 8192 + (size_t)half * 4096;
  const float* hp = h + rowbase;
  const float* rp = rec + rowbase;
  const float* np2 = nid + (size_t)c * 8192 + (size_t)half * 4096;
  for (int s = 0; s < 4; ++s) {
    int e = (s * 256 + t) * 4;
    int row = e >> 6, col = e & 63;
    f32x4 v1 = *(const f32x4*)(hp + e);
    f32x4 v2 = *(const f32x4*)(rp + e);
    f32x4 v3 = *(const f32x4*)(np2 + e);
#pragma unroll
    for (int j = 0; j < 4; ++j) {
      xs[row][col + j] = (bf16_t)v1[j];
      xs[row][64 + col + j] = (bf16_t)v2[j];
      xs[row][128 + col + j] = (bf16_t)v3[j];
    }
  }
  int wave = t >> 6, l = t & 63, lr = l & 15, kg = l >> 4;
  const bf16_t* w1b = wbf;
  const bf16_t* w2b = wbf + 49152;
  const bf16_t* w3b = wbf + 65536;
  const bf16_t* w4b = wbf + 98304;

  // ---- phase A: h_new = tanh(W2 @ tanh(W1 @ [h|rec|nid] + b1) + b2) ----
  f32x4 acc2[4] = {};
  for (int hc = 0; hc < 4; ++hc) {
    __syncthreads();  // protect wc from previous chunk's readers
    for (int s = 0; s < 6; ++s) {  // stage state_w1 chunk [64][192]
      int e = (s * 256 + t) * 8;
      int hh = e / 192, kk = e % 192;
      *(bf16x8*)&wc[hh][kk] = *(const bf16x8*)(w1b + (size_t)(hc * 64 + hh) * 192 + kk);
    }
    __syncthreads();
    f32x4 a1[4] = {};
#pragma unroll
    for (int ks = 0; ks < 6; ++ks) {
      int kof = ks * 32 + kg * 8;
      bf16x8 af = *(const bf16x8*)&xs[wave * 16 + lr][kof];
#pragma unroll
      for (int ni = 0; ni < 4; ++ni) {
        bf16x8 bfr = *(const bf16x8*)&wc[ni * 16 + lr][kof];
        a1[ni] = mfma16(af, bfr, a1[ni]);
      }
    }
#pragma unroll
    for (int ni = 0; ni < 4; ++ni) {  // bias+tanh -> hs (rows wave-private)
      float bias = sb1[hc * 64 + ni * 16 + lr];
#pragma unroll
      for (int r = 0; r < 4; ++r)
        hs[wave * 16 + kg * 4 + r][ni * 16 + lr] = (bf16_t)fast_tanh(a1[ni][r] + bias);
    }
#pragma unroll
    for (int ks = 0; ks < 2; ++ks) {  // GEMM2 accumulate, B from global bf16 (L2 hot)
      int kof = ks * 32 + kg * 8;
      bf16x8 af = *(const bf16x8*)&hs[wave * 16 + lr][kof];
#pragma unroll
      for (int ni = 0; ni < 4; ++ni) {
        bf16x8 bfr = *(const bf16x8*)(w2b + (size_t)(ni * 16 + lr) * 256 + hc * 64 + kof);
        acc2[ni] = mfma16(af, bfr, acc2[ni]);
      }
    }
  }
  float* ohp = out_h + rowbase;
#pragma unroll
  for (int ni = 0; ni < 4; ++ni) {
    float bias = sb2[ni * 16 + lr];
#pragma unroll
    for (int r = 0; r < 4; ++r) {
      int row = wave * 16 + kg * 4 + r, col = ni * 16 + lr;
      float v = fast_tanh(acc2[ni][r] + bias);
      ohp[row * 64 + col] = v;
      hs[row][col] = (bf16_t)v;  // h_new bf16, wave-private rows
    }
  }

  // ---- phase B: msg_new; msg_in k: 0-63 = h_new (hs), 64-127 = received (xs) ----
  f32x4 acc3[4] = {};
  for (int hc = 0; hc < 4; ++hc) {
    __syncthreads();
    for (int s = 0; s < 4; ++s) {  // stage msg_w1 chunk [64][128]
      int e = (s * 256 + t) * 8;
      int hh = e >> 7, kk = e & 127;
      *(bf16x8*)&wc[hh][kk] = *(const bf16x8*)(w3b + (size_t)(hc * 64 + hh) * 128 + kk);
    }
    __syncthreads();
    f32x4 g3[4] = {};
#pragma unroll
    for (int ks = 0; ks < 4; ++ks) {
      int kof = ks * 32 + kg * 8;
      bf16x8 af;
      if (ks < 2) af = *(const bf16x8*)&hs[wave * 16 + lr][kof];
      else        af = *(const bf16x8*)&xs[wave * 16 + lr][kof];  // k in [64,128): received
#pragma unroll
      for (int ni = 0; ni < 4; ++ni) {
        bf16x8 bfr = *(const bf16x8*)&wc[ni * 16 + lr][kof];
        g3[ni] = mfma16(af, bfr, g3[ni]);
      }
    }
#pragma unroll
    for (int ni = 0; ni < 4; ++ni) {  // tanh -> hid2 chunk in xs cols 128..191
      float bias = msb1[hc * 64 + ni * 16 + lr];
#pragma unroll
      for (int r = 0; r < 4; ++r)
        xs[wave * 16 + kg * 4 + r][128 + ni * 16 + lr] = (bf16_t)fast_tanh(g3[ni][r] + bias);
    }
#pragma unroll
    for (int ks = 0; ks < 2; ++ks) {
      int kof = ks * 32 + kg * 8;
      bf16x8 af = *(const bf16x8*)&xs[wave * 16 + lr][128 + kof];
#pragma unroll
      for (int ni = 0; ni < 4; ++ni) {
        bf16x8 bfr = *(const bf16x8*)(w4b + (size_t)(ni * 16 + lr) * 256 + hc * 64 + kof);
        acc3[ni] = mfma16(af, bfr, acc3[ni]);
      }
    }
  }
  float* omp = out_m + rowbase;
#pragma unroll
  for (int ni = 0; ni < 4; ++ni) {
    float bias = msb2[ni * 16 + lr];
#pragma unroll
    for (int r = 0; r < 4; ++r) {
      int row = wave * 16 + kg * 4 + r, col = ni * 16 + lr;
      omp[row * 64 + col] = fast_tanh(acc3[ni][r] + bias);
    }
  }
}

// ---- K3: modulator input assembly + first layer (f32 exact) ----
__global__ __launch_bounds__(256) void k_mod(
    const float* __restrict__ out_h, const float* __restrict__ out_m,
    const float* __restrict__ decay, const float* __restrict__ rdrift,
    const float* __restrict__ sml, const float* __restrict__ smf,
    const float* __restrict__ wstats, const float* __restrict__ mw1,
    const float* __restrict__ mb1, float* __restrict__ hidden) {
  int bc = blockIdx.x, c = bc & 63, b = bc >> 6;
  __shared__ float red[256];
  __shared__ float modin[133];
  int t = threadIdx.x, d = t & 63, q = t >> 6;
  const float* hp = out_h + (size_t)bc * 8192;
  const float* mp = out_m + (size_t)bc * 8192;
  float s1 = 0.f, s2 = 0.f;
  for (int i = q * 32; i < q * 32 + 32; ++i) { s1 += hp[i * 64 + d]; s2 += mp[i * 64 + d]; }
  red[t] = s1; __syncthreads();
  if (q == 0) modin[d] = (red[d] + red[64 + d] + red[128 + d] + red[192 + d]) * (1.f / 128.f);
  __syncthreads();
  red[t] = s2; __syncthreads();
  if (q == 0) modin[64 + d] = (red[d] + red[64 + d] + red[128 + d] + red[192 + d]) * (1.f / 128.f);
  __syncthreads();
  red[t] = (t < 128) ? decay[(size_t)bc * 128 + t] : 0.f;
  __syncthreads();
  if (t == 0) {
    float s = 0.f;
    for (int i = 0; i < 128; ++i) s += red[i];
    modin[128] = wstats[bc] * (1.f / 16384.f);
    modin[129] = s * (1.f / 128.f);
    modin[130] = rdrift[bc];
    modin[131] = sml[b];
    modin[132] = smf[b];
  }
  __syncthreads();
  if (t < 64) {
    const float* w = mw1 + (size_t)c * 133 * 64;
    float a = mb1[c * 64 + t];
    for (int i = 0; i < 133; ++i) a += modin[i] * w[i * 64 + t];
    hidden[(size_t)bc * 64 + t] = fast_tanh(a);
  }
}

// ---- K4: mod_out = hidden @ mod_w2 + b2; W_new = W + dW; decay_new ----
__global__ __launch_bounds__(256) void k_apply(
    const float* __restrict__ hidden, const float* __restrict__ mw2,
    const float* __restrict__ mb2, const float* __restrict__ W,
    const float* __restrict__ decay, float* __restrict__ out_W,
    float* __restrict__ out_d) {
  int c = blockIdx.y, ch = blockIdx.x, t = threadIdx.x;
  __shared__ float hid[8][64];
  int b0 = t >> 6, h0 = t & 63;
  hid[b0][h0] = hidden[(size_t)(b0 * 64 + c) * 64 + h0];
  hid[b0 + 4][h0] = hidden[(size_t)((b0 + 4) * 64 + c) * 64 + h0];
  __syncthreads();
  int o = ch * 1024 + t * 4;
  if (o >= 16512) return;
  const float* w2 = mw2 + (size_t)c * 64 * 16512 + o;
  f32x4 bias = *(const f32x4*)(mb2 + (size_t)c * 16512 + o);
  f32x4 acc[8];
#pragma unroll
  for (int b = 0; b < 8; ++b) acc[b] = bias;
  for (int hh = 0; hh < 64; ++hh) {
    f32x4 wv = *(const f32x4*)(w2 + (size_t)hh * 16512);
#pragma unroll
    for (int b = 0; b < 8; ++b) acc[b] += hid[b][hh] * wv;
  }
  if (o < 16384) {
#pragma unroll
    for (int b = 0; b < 8; ++b) {
      size_t idx = (size_t)(b * 64 + c) * 16384 + o;
      f32x4 wv = *(const f32x4*)(W + idx);
      *(f32x4*)(out_W + idx) = wv + acc[b];
    }
  } else {
    int i = o - 16384;
#pragma unroll
    for (int b = 0; b < 8; ++b) {
      size_t idx = (size_t)(b * 64 + c) * 128 + i;
      f32x4 dv = *(const f32x4*)(decay + idx);
      *(f32x4*)(out_d + idx) = dv + acc[b];
    }
  }
}

extern "C" void kernel_launch(void* const* d_in, const int* in_sizes, int n_in,
                              void* d_out, int out_size, void* d_ws, size_t ws_size,
                              hipStream_t stream) {
  const float* h = (const float*)d_in[0];
  const float* msg = (const float*)d_in[1];
  const float* W = (const float*)d_in[2];
  const float* decay = (const float*)d_in[3];
  const float* rdrift = (const float*)d_in[4];
  const float* sml = (const float*)d_in[5];
  const float* smf = (const float*)d_in[6];
  const float* Haug = (const float*)d_in[7];
  const float* nid = (const float*)d_in[8];
  const float* sw1 = (const float*)d_in[9];
  const float* sb1 = (const float*)d_in[10];
  const float* sw2 = (const float*)d_in[11];
  const float* sb2 = (const float*)d_in[12];
  const float* mw1 = (const float*)d_in[13];
  const float* mb1 = (const float*)d_in[14];
  const float* mw2 = (const float*)d_in[15];
  const float* mb2 = (const float*)d_in[16];
  const float* injw = (const float*)d_in[17];
  const float* injb = (const float*)d_in[18];
  const float* modw1 = (const float*)d_in[19];
  const float* modb1 = (const float*)d_in[20];
  const float* modw2 = (const float*)d_in[21];
  const float* modb2 = (const float*)d_in[22];

  float* out = (float*)d_out;
  float* out_h = out;                 // [8,64,128,64]
  float* out_m = out + 4194304;       // [8,64,128,64]
  float* out_W = out + 8388608;       // [8,64,128,128]
  float* out_d = out + 16777216;      // [8,64,128]

  char* wsb = (char*)d_ws;
  float* rec = (float*)wsb;                                  // 16 MB
  float* wstats = (float*)(wsb + 16777216);                  // 2 KB (pad to 4K)
  float* hidden = (float*)(wsb + 16777216 + 4096);           // 128 KB
  bf16_t* wbf = (bf16_t*)(wsb + 16777216 + 4096 + 131072);   // 224 KB

  k_convert<<<448, 256, 0, stream>>>(sw1, sw2, mw1, mw2, wbf);
  k_received<<<512, 256, 0, stream>>>(W, msg, Haug, injw, injb, rec, wstats);
  k_mlp<<<1024, 256, 0, stream>>>(h, rec, nid, wbf, sb1, sb2, mb1, mb2, out_h, out_m);
  k_mod<<<512, 256, 0, stream>>>(out_h, out_m, decay, rdrift, sml, smf, wstats,
                                 modw1, modb1, hidden);
  k_apply<<<dim3(17, 64), 256, 0, stream>>>(hidden, modw2, modb2, W, decay, out_W, out_d);
}